// Round 6
// baseline (3650.109 us; speedup 1.0000x reference)
//
#include <hip/hip_runtime.h>
#include <hip/hip_bf16.h>
#include <hip/hip_cooperative_groups.h>

namespace cg = cooperative_groups;

// ---------------------------------------------------------------------------
// Decoder_996432412985: attention LSTM decoder on MI355X.
// B=64, FMAP=512, ENC=256, DEC=512, ATTN=256, NC+2=98, T+1=31, H=8, W=32.
// Inputs fp32 -> bf16 ws copies; bf16 MFMA + fp32 acc; outputs fp32.
// R6: the 31x4 serial launches (~82us/step) replaced by ONE cooperative
// kernel (64 blocks): lstm0 | sync | lstm1 | sync | attn(+eh/fc GEMV) | sync.
// Prep + conv unchanged from passing R5.
// ---------------------------------------------------------------------------

typedef __bf16 bf16_8 __attribute__((ext_vector_type(8)));
typedef __bf16 bf16_4 __attribute__((ext_vector_type(4)));
typedef float f32x4 __attribute__((ext_vector_type(4)));

typedef __hip_bfloat16 bf;

__device__ __forceinline__ float b2f(bf h) { return __bfloat162float(h); }
__device__ __forceinline__ bf f2b(float f) { return __float2bfloat16(f); }
__device__ __forceinline__ float sigm(float x) { return 1.0f / (1.0f + __expf(-x)); }
__device__ __forceinline__ float tanh_f(float x) { return 1.0f - 2.0f / (1.0f + __expf(2.0f * x)); }
__device__ __forceinline__ f32x4 mfma16(bf16_8 a, bf16_8 b, f32x4 c) {
    return __builtin_amdgcn_mfma_f32_16x16x32_bf16(a, b, c, 0, 0, 0);
}

#define NB 64
#define FMAP 512
#define ENC 256
#define DEC 512
#define ATTN 256
#define NC2 98
#define TT 31
#define HW 256

// ------------------------- dtype normalization -----------------------------

__global__ void k_detect(const int* __restrict__ t32, int* __restrict__ flags) {
    __shared__ int i64f;
    int tid = threadIdx.x;
    if (tid == 0) i64f = 1;
    __syncthreads();
    for (int i = tid; i < 960; i += 256)
        if (t32[2 * i + 1] != 0) i64f = 0;
    __syncthreads();
    if (tid == 0) { flags[0] = 0; flags[1] = i64f; }
}

#define N_CVT 18
struct CvtTab {
    const void* src[N_CVT];
    unsigned long long off[N_CVT];
    int n[N_CVT];
};

__global__ void k_cvt(CvtTab tab, unsigned char* __restrict__ ws) {
    int id = blockIdx.y;
    int n = tab.n[id];
    bf* dst = (bf*)(ws + tab.off[id]);
    const float* sf = (const float*)tab.src[id];
    for (int i = blockIdx.x * 256 + threadIdx.x; i < n; i += 256 * gridDim.x)
        dst[i] = f2b(sf[i]);
}

// ------------------------- prep kernels ------------------------------------

__global__ void k_init_state(const float* __restrict__ h0, const float* __restrict__ c0,
                             bf* __restrict__ h0b, bf* __restrict__ h1b,
                             float* __restrict__ c0f, float* __restrict__ c1f) {
    int i = blockIdx.x * 256 + threadIdx.x;
    if (i >= NB * DEC) return;
    h0b[i] = f2b(h0[i]);
    h1b[i] = f2b(h0[NB * DEC + i]);
    c0f[i] = c0[i];
    c1f[i] = c0[NB * DEC + i];
}

__global__ void k_embed(const int* __restrict__ target, const bf* __restrict__ emb,
                        bf* __restrict__ x_seq, const int* __restrict__ flags) {
    int t = blockIdx.x, b = blockIdx.y, e = threadIdx.x;
    int lab = 0;
    if (t > 0) {
        int idx = b * 30 + (t - 1);
        lab = flags[1] ? target[2 * idx] : target[idx];
    }
    lab = min(max(lab, 0), 96);
    x_seq[(t * NB + b) * ENC + e] = emb[lab * ENC + e];
}

__global__ void k_wt(const bf* __restrict__ ew, bf* __restrict__ wt) {
    int dydx = blockIdx.x, a = blockIdx.y;
    for (int c = threadIdx.x; c < FMAP; c += 256)
        wt[(dydx * ATTN + a) * FMAP + c] = ew[(a * FMAP + c) * 9 + dydx];
}

// conv3x3 as MFMA GEMM with LDS-staged transpose (unchanged from R5).
__global__ __launch_bounds__(256) void k_conv(const bf* __restrict__ fmap,
                                              const bf* __restrict__ wt,
                                              const bf* __restrict__ efb,
                                              bf* __restrict__ ef) {
    __shared__ __align__(16) __bf16 T[257 * 72];
    int b = blockIdx.x;
    int aHalf = blockIdx.y;
    int pHalf = blockIdx.z;
    int tid = threadIdx.x, wv = tid >> 6, lane = tid & 63;
    int q = lane >> 4, l = lane & 15;
    int abase = aHalf * 128 + wv * 32;

    for (int i = tid; i < 72; i += 256) T[256 * 72 + i] = (__bf16)0.0f;

    f32x4 acc[2][8] = {};
    for (int cQ = 0; cQ < 8; cQ++) {
        __syncthreads();
        for (int cc = 0; cc < 16; cc++) {
            int c_l = cc * 4 + wv;
            int cg = cQ * 64 + c_l;
            bf16_4 v = *(const bf16_4*)(fmap + ((size_t)(b * FMAP + cg)) * HW + lane * 4);
#pragma unroll
            for (int j = 0; j < 4; j++) T[(lane * 4 + j) * 72 + c_l] = v[j];
        }
        __syncthreads();
        for (int dydx = 0; dydx < 9; dydx++) {
            int dy = dydx / 3, dx = dydx % 3;
            int rowv[8];
#pragma unroll
            for (int nt = 0; nt < 8; nt++) {
                int y = pHalf * 4 + (nt >> 1);
                int yp = y + dy - 1;
                int x = (nt & 1) * 16 + l;
                int xp = x + dx - 1;
                bool ok = (yp >= 0 && yp < 8 && xp >= 0 && xp < 32);
                rowv[nt] = ok ? (yp * 32 + xp) : 256;
            }
            const bf* wtd = wt + ((size_t)dydx * ATTN) * FMAP;
#pragma unroll
            for (int ck = 0; ck < 2; ck++) {
                int kg = cQ * 64 + ck * 32 + q * 8;
                bf16_8 afr[2];
#pragma unroll
                for (int mt = 0; mt < 2; mt++)
                    afr[mt] = *(const bf16_8*)(wtd + (abase + mt * 16 + l) * FMAP + kg);
#pragma unroll
                for (int nt = 0; nt < 8; nt++) {
                    bf16_8 bfr = *(const bf16_8*)(T + rowv[nt] * 72 + ck * 32 + q * 8);
                    acc[0][nt] = mfma16(afr[0], bfr, acc[0][nt]);
                    acc[1][nt] = mfma16(afr[1], bfr, acc[1][nt]);
                }
            }
        }
    }
#pragma unroll
    for (int mt = 0; mt < 2; mt++)
#pragma unroll
        for (int nt = 0; nt < 8; nt++) {
            int a0 = abase + mt * 16 + q * 4;
            int pos = pHalf * 128 + nt * 16 + l;
            bf16_4 o;
#pragma unroll
            for (int r = 0; r < 4; r++) o[r] = f2b(acc[mt][nt][r] + b2f(efb[a0 + r]));
            *(bf16_4*)(ef + ((size_t)(b * HW + pos)) * ATTN + a0) = o;
        }
}

// ------------------- fused cooperative step-loop kernel ---------------------

struct StepArgs {
    const bf *x_seq, *Wih0, *Whh0, *bih0, *bhh0, *Wih1, *Whh1, *bih1, *bhh1;
    const bf *e_lstm_w, *e_lstm_b, *fc_w, *fc_b, *a_w, *a_b, *ef, *fmap;
    bf *h0b, *h1b;
    float *c0f, *c1f;
    float *out_logits, *out_masks, *out_glimpses;
};

__global__ __launch_bounds__(256, 1) void k_steps(StepArgs A) {
    cg::grid_group grid = cg::this_grid();
    const int blk = blockIdx.x, tid = threadIdx.x;
    const int wv = tid >> 6, lane = tid & 63;
    const int q = lane >> 4, l = lane & 15;

    __shared__ float h1s[DEC], ehs[ATTN], fcs[NC2], aws[ATTN], msk[HW],
                     gls[FMAP], red[256];
    aws[tid] = b2f(A.a_w[tid]);  // constant across steps
    __syncthreads();

    for (int t = 0; t < TT; t++) {
        const int cur = t & 1;
        const bf* h0prev = A.h0b + cur * 32768;
        bf*       h0new  = A.h0b + (cur ^ 1) * 32768;
        const bf* h1prev = A.h1b + cur * 32768;
        bf*       h1new  = A.h1b + (cur ^ 1) * 32768;

        // -------- phase A: lstm0 (blocks 0..31) --------
        if (blk < 32) {
            const bf* xt = A.x_seq + (size_t)t * NB * ENC;
            int d0 = blk * 16;
            f32x4 acc[4] = {};
            for (int k0 = 0; k0 < ENC; k0 += 32) {
                bf16_8 af = *(const bf16_8*)(xt + (wv * 16 + l) * ENC + k0 + q * 8);
#pragma unroll
                for (int g = 0; g < 4; g++) {
                    bf16_8 bfr = *(const bf16_8*)(A.Wih0 + (g * 512 + d0 + l) * ENC + k0 + q * 8);
                    acc[g] = mfma16(af, bfr, acc[g]);
                }
            }
            for (int k0 = 0; k0 < DEC; k0 += 32) {
                bf16_8 af = *(const bf16_8*)(h0prev + (wv * 16 + l) * DEC + k0 + q * 8);
#pragma unroll
                for (int g = 0; g < 4; g++) {
                    bf16_8 bfr = *(const bf16_8*)(A.Whh0 + (g * 512 + d0 + l) * DEC + k0 + q * 8);
                    acc[g] = mfma16(af, bfr, acc[g]);
                }
            }
            int d = d0 + l;
            float bi[4];
#pragma unroll
            for (int g = 0; g < 4; g++)
                bi[g] = b2f(A.bih0[g * 512 + d]) + b2f(A.bhh0[g * 512 + d]);
#pragma unroll
            for (int r = 0; r < 4; r++) {
                int bb = wv * 16 + q * 4 + r;
                float gi = sigm(acc[0][r] + bi[0]);
                float gf = sigm(acc[1][r] + bi[1]);
                float gg = tanh_f(acc[2][r] + bi[2]);
                float go = sigm(acc[3][r] + bi[3]);
                float c = gf * A.c0f[bb * DEC + d] + gi * gg;
                A.c0f[bb * DEC + d] = c;
                h0new[bb * DEC + d] = f2b(go * tanh_f(c));
            }
        }
        grid.sync();

        // -------- phase B: lstm1 (blocks 0..31) --------
        if (blk < 32) {
            int d0 = blk * 16;
            f32x4 acc[4] = {};
            for (int ph = 0; ph < 2; ph++) {
                const bf* Ain = ph ? h1prev : h0new;
                const bf* Wp = ph ? A.Whh1 : A.Wih1;
                for (int k0 = 0; k0 < DEC; k0 += 32) {
                    bf16_8 af = *(const bf16_8*)(Ain + (wv * 16 + l) * DEC + k0 + q * 8);
#pragma unroll
                    for (int g = 0; g < 4; g++) {
                        bf16_8 bfr = *(const bf16_8*)(Wp + (g * 512 + d0 + l) * DEC + k0 + q * 8);
                        acc[g] = mfma16(af, bfr, acc[g]);
                    }
                }
            }
            int d = d0 + l;
            float bi[4];
#pragma unroll
            for (int g = 0; g < 4; g++)
                bi[g] = b2f(A.bih1[g * 512 + d]) + b2f(A.bhh1[g * 512 + d]);
#pragma unroll
            for (int r = 0; r < 4; r++) {
                int bb = wv * 16 + q * 4 + r;
                float gi = sigm(acc[0][r] + bi[0]);
                float gf = sigm(acc[1][r] + bi[1]);
                float gg = tanh_f(acc[2][r] + bi[2]);
                float go = sigm(acc[3][r] + bi[3]);
                float c = gf * A.c1f[bb * DEC + d] + gi * gg;
                A.c1f[bb * DEC + d] = c;
                h1new[bb * DEC + d] = f2b(go * tanh_f(c));
            }
        }
        grid.sync();

        // -------- phase C: attn for batch row b = blk (all 64 blocks) --------
        {
            int b = blk;
            for (int i = tid; i < DEC; i += 256) h1s[i] = b2f(h1new[b * DEC + i]);
            __syncthreads();

            // eh[tid] and (tid<98) fch[tid]: GEMV against h1s
            {
                float s = 0.0f;
                const bf16_8* wr = (const bf16_8*)(A.e_lstm_w + (size_t)tid * DEC);
#pragma unroll 4
                for (int k8 = 0; k8 < DEC / 8; k8++) {
                    bf16_8 w8 = wr[k8];
#pragma unroll
                    for (int j = 0; j < 8; j++) s += (float)w8[j] * h1s[k8 * 8 + j];
                }
                ehs[tid] = s + b2f(A.e_lstm_b[tid]);
                if (tid < NC2) {
                    float s2 = 0.0f;
                    const bf16_8* wr2 = (const bf16_8*)(A.fc_w + (size_t)tid * (DEC + FMAP));
#pragma unroll 4
                    for (int k8 = 0; k8 < DEC / 8; k8++) {
                        bf16_8 w8 = wr2[k8];
#pragma unroll
                        for (int j = 0; j < 8; j++) s2 += (float)w8[j] * h1s[k8 * 8 + j];
                    }
                    fcs[tid] = s2 + b2f(A.fc_b[tid]);
                }
            }
            __syncthreads();

            // score[pos=tid]
            float sc;
            {
                const bf16_8* er = (const bf16_8*)(A.ef + ((size_t)b * HW + tid) * ATTN);
                float s0 = 0.f, s1 = 0.f, s2 = 0.f, s3 = 0.f;
#pragma unroll 4
                for (int a8 = 0; a8 < ATTN / 8; a8++) {
                    bf16_8 e8 = er[a8];
                    int a = a8 * 8;
                    s0 += aws[a + 0] * tanh_f(ehs[a + 0] + (float)e8[0]);
                    s1 += aws[a + 1] * tanh_f(ehs[a + 1] + (float)e8[1]);
                    s2 += aws[a + 2] * tanh_f(ehs[a + 2] + (float)e8[2]);
                    s3 += aws[a + 3] * tanh_f(ehs[a + 3] + (float)e8[3]);
                    s0 += aws[a + 4] * tanh_f(ehs[a + 4] + (float)e8[4]);
                    s1 += aws[a + 5] * tanh_f(ehs[a + 5] + (float)e8[5]);
                    s2 += aws[a + 6] * tanh_f(ehs[a + 6] + (float)e8[6]);
                    s3 += aws[a + 7] * tanh_f(ehs[a + 7] + (float)e8[7]);
                }
                sc = (s0 + s1) + (s2 + s3) + b2f(A.a_b[0]);
                red[tid] = sc;
            }
            __syncthreads();
            for (int off = 128; off > 0; off >>= 1) {
                if (tid < off) red[tid] = fmaxf(red[tid], red[tid + off]);
                __syncthreads();
            }
            float mx = red[0];
            __syncthreads();
            float ex = __expf(sc - mx);
            red[tid] = ex;
            __syncthreads();
            for (int off = 128; off > 0; off >>= 1) {
                if (tid < off) red[tid] += red[tid + off];
                __syncthreads();
            }
            float mk = ex / red[0];
            msk[tid] = mk;
            A.out_masks[(b * TT + t) * HW + tid] = mk;
            __syncthreads();

            // glimpse: thread-per-channel x2
            {
                int c0 = tid, c1 = tid + 256;
                const bf16_8* r0 = (const bf16_8*)(A.fmap + ((size_t)b * FMAP + c0) * HW);
                const bf16_8* r1 = (const bf16_8*)(A.fmap + ((size_t)b * FMAP + c1) * HW);
                float g0 = 0.f, g1 = 0.f;
#pragma unroll 4
                for (int p8 = 0; p8 < HW / 8; p8++) {
                    bf16_8 f0 = r0[p8], f1 = r1[p8];
#pragma unroll
                    for (int j = 0; j < 8; j++) {
                        float m = msk[p8 * 8 + j];
                        g0 += (float)f0[j] * m;
                        g1 += (float)f1[j] * m;
                    }
                }
                gls[c0] = g0;
                gls[c1] = g1;
                float* og = A.out_glimpses + ((size_t)b * TT + t) * FMAP;
                og[c0] = g0;
                og[c1] = g1;
            }
            __syncthreads();

            // logits: glimpse half of fc + precomputed h1-half
            {
                int cls = tid >> 1, half = tid & 1;
                float s = 0.0f;
                if (cls < NC2) {
                    const bf16_8* wr =
                        (const bf16_8*)(A.fc_w + (size_t)cls * (DEC + FMAP) + DEC + half * 256);
                    const float* act = gls + half * 256;
#pragma unroll 4
                    for (int k8 = 0; k8 < 32; k8++) {
                        bf16_8 w8 = wr[k8];
#pragma unroll
                        for (int j = 0; j < 8; j++) s += (float)w8[j] * act[k8 * 8 + j];
                    }
                }
                red[tid] = s;
                __syncthreads();
                if (cls < NC2 && half == 0)
                    A.out_logits[(b * TT + t) * NC2 + cls] = red[tid] + red[tid + 1] + fcs[cls];
            }
            __syncthreads();  // protect shared bufs before next step's phase C
        }
        grid.sync();
    }
}

// ------------------------------ host ---------------------------------------

extern "C" void kernel_launch(void* const* d_in, const int* in_sizes, int n_in,
                              void* d_out, int out_size, void* d_ws, size_t ws_size,
                              hipStream_t stream) {
    float* out = (float*)d_out;
    float* out_logits   = out;
    float* out_masks    = out + 64 * 31 * 98;
    float* out_glimpses = out + 64 * 31 * (98 + 256);

    unsigned char* ws = (unsigned char*)d_ws;
    unsigned long long off = 0;
    auto carve = [&](size_t bytes) {
        unsigned long long o = off;
        off = (off + bytes + 15ULL) & ~15ULL;
        return o;
    };

    unsigned long long o_flags = carve(64);
    static const int cvt_in[N_CVT] = {5, 6, 7, 8, 9, 10, 11, 12, 13, 14, 15, 16, 17, 18, 19, 20, 21, 0};
    static const int cvt_n[N_CVT] = {
        97 * 256, 2048 * 256, 2048 * 512, 2048, 2048,
        2048 * 512, 2048 * 512, 2048, 2048,
        256 * 512, 256, 256 * 512 * 9, 256, 256, 1,
        98 * 1024, 98, 64 * 512 * 256
    };
    CvtTab tab;
    for (int i = 0; i < N_CVT; i++) {
        tab.src[i] = d_in[cvt_in[i]];
        tab.n[i] = cvt_n[i];
        tab.off[i] = carve((size_t)cvt_n[i] * 2);
    }
    const bf* emb_c    = (const bf*)(ws + tab.off[0]);
    const bf* Wih0_c   = (const bf*)(ws + tab.off[1]);
    const bf* Whh0_c   = (const bf*)(ws + tab.off[2]);
    const bf* bih0_c   = (const bf*)(ws + tab.off[3]);
    const bf* bhh0_c   = (const bf*)(ws + tab.off[4]);
    const bf* Wih1_c   = (const bf*)(ws + tab.off[5]);
    const bf* Whh1_c   = (const bf*)(ws + tab.off[6]);
    const bf* bih1_c   = (const bf*)(ws + tab.off[7]);
    const bf* bhh1_c   = (const bf*)(ws + tab.off[8]);
    const bf* e_lstm_w_c = (const bf*)(ws + tab.off[9]);
    const bf* e_lstm_b_c = (const bf*)(ws + tab.off[10]);
    const bf* e_fmap_w_c = (const bf*)(ws + tab.off[11]);
    const bf* e_fmap_b_c = (const bf*)(ws + tab.off[12]);
    const bf* a_w_c    = (const bf*)(ws + tab.off[13]);
    const bf* a_b_c    = (const bf*)(ws + tab.off[14]);
    const bf* fc_w_c   = (const bf*)(ws + tab.off[15]);
    const bf* fc_b_c   = (const bf*)(ws + tab.off[16]);
    const bf* fmap_c   = (const bf*)(ws + tab.off[17]);

    bf*    wt    = (bf*)(ws + carve((size_t)9 * 256 * 512 * 2));
    bf*    ef    = (bf*)(ws + carve((size_t)64 * 256 * 256 * 2));
    bf*    x_seq = (bf*)(ws + carve((size_t)31 * 64 * 256 * 2));
    bf*    h0b   = (bf*)(ws + carve(2 * 65536));
    bf*    h1b   = (bf*)(ws + carve(2 * 65536));
    float* c0f   = (float*)(ws + carve(131072));
    float* c1f   = (float*)(ws + carve(131072));
    int*   flags = (int*)(ws + o_flags);

    k_detect<<<1, 256, 0, stream>>>((const int*)d_in[3], flags);
    k_cvt<<<dim3(256, N_CVT), 256, 0, stream>>>(tab, ws);
    k_init_state<<<128, 256, 0, stream>>>((const float*)d_in[1], (const float*)d_in[2],
                                          h0b, h1b, c0f, c1f);
    k_embed<<<dim3(TT, NB), 256, 0, stream>>>((const int*)d_in[3], emb_c, x_seq, flags);
    k_wt<<<dim3(9, ATTN), 256, 0, stream>>>(e_fmap_w_c, wt);
    k_conv<<<dim3(NB, 2, 2), 256, 0, stream>>>(fmap_c, wt, e_fmap_b_c, ef);

    StepArgs sa;
    sa.x_seq = x_seq; sa.Wih0 = Wih0_c; sa.Whh0 = Whh0_c;
    sa.bih0 = bih0_c; sa.bhh0 = bhh0_c;
    sa.Wih1 = Wih1_c; sa.Whh1 = Whh1_c; sa.bih1 = bih1_c; sa.bhh1 = bhh1_c;
    sa.e_lstm_w = e_lstm_w_c; sa.e_lstm_b = e_lstm_b_c;
    sa.fc_w = fc_w_c; sa.fc_b = fc_b_c; sa.a_w = a_w_c; sa.a_b = a_b_c;
    sa.ef = ef; sa.fmap = fmap_c;
    sa.h0b = h0b; sa.h1b = h1b; sa.c0f = c0f; sa.c1f = c1f;
    sa.out_logits = out_logits; sa.out_masks = out_masks;
    sa.out_glimpses = out_glimpses;

    void* kargs[] = {&sa};
    hipLaunchCooperativeKernel((const void*)k_steps, dim3(64), dim3(256), kargs, 0, stream);
}

// Round 8
// 2929.155 us; speedup vs baseline: 1.2461x; 1.2461x over previous
//
#include <hip/hip_runtime.h>
#include <hip/hip_bf16.h>

// ---------------------------------------------------------------------------
// Decoder_996432412985: attention LSTM decoder on MI355X.
// B=64, FMAP=512, ENC=256, DEC=512, ATTN=256, NC+2=98, T+1=31, H=8, W=32.
// Inputs fp32 -> bf16 ws copies; bf16 MFMA + fp32 acc; outputs fp32.
// R8 == R7 intent (conv via global padT, no LDS bank conflicts; 3 launches/
// step) with the __bf16/__hip_bfloat16 assignment ambiguity in k_padT fixed.
// ---------------------------------------------------------------------------

typedef __bf16 bf16_8 __attribute__((ext_vector_type(8)));
typedef __bf16 bf16_4 __attribute__((ext_vector_type(4)));
typedef __bf16 bf16_2 __attribute__((ext_vector_type(2)));
typedef float f32x4 __attribute__((ext_vector_type(4)));

typedef __hip_bfloat16 bf;

__device__ __forceinline__ float b2f(bf h) { return __bfloat162float(h); }
__device__ __forceinline__ bf f2b(float f) { return __float2bfloat16(f); }
__device__ __forceinline__ float sigm(float x) { return 1.0f / (1.0f + __expf(-x)); }
__device__ __forceinline__ float tanh_f(float x) { return 1.0f - 2.0f / (1.0f + __expf(2.0f * x)); }
__device__ __forceinline__ f32x4 mfma16(bf16_8 a, bf16_8 b, f32x4 c) {
    return __builtin_amdgcn_mfma_f32_16x16x32_bf16(a, b, c, 0, 0, 0);
}

#define NB 64
#define FMAP 512
#define ENC 256
#define DEC 512
#define ATTN 256
#define NC2 98
#define TT 31
#define HW 256
#define PW 34
#define PPOS 340  // 10*34 padded spatial

// ------------------------- dtype normalization -----------------------------

__global__ void k_detect(const int* __restrict__ t32, int* __restrict__ flags) {
    __shared__ int i64f;
    int tid = threadIdx.x;
    if (tid == 0) i64f = 1;
    __syncthreads();
    for (int i = tid; i < 960; i += 256)
        if (t32[2 * i + 1] != 0) i64f = 0;
    __syncthreads();
    if (tid == 0) { flags[0] = 0; flags[1] = i64f; }
}

#define N_CVT 17
struct CvtTab {
    const void* src[N_CVT];
    unsigned long long off[N_CVT];
    int n[N_CVT];
};

__global__ void k_cvt(CvtTab tab, unsigned char* __restrict__ ws) {
    int id = blockIdx.y;
    int n = tab.n[id];
    bf* dst = (bf*)(ws + tab.off[id]);
    const float* sf = (const float*)tab.src[id];
    for (int i = blockIdx.x * 256 + threadIdx.x; i < n; i += 256 * gridDim.x)
        dst[i] = f2b(sf[i]);
}

// ------------------------- prep kernels ------------------------------------

__global__ void k_init_state(const float* __restrict__ h0, const float* __restrict__ c0,
                             bf* __restrict__ h0b, bf* __restrict__ h1b,
                             float* __restrict__ c0f, float* __restrict__ c1f) {
    int i = blockIdx.x * 256 + threadIdx.x;
    if (i >= NB * DEC) return;
    h0b[i] = f2b(h0[i]);
    h1b[i] = f2b(h0[NB * DEC + i]);
    c0f[i] = c0[i];
    c1f[i] = c0[NB * DEC + i];
}

__global__ void k_embed(const int* __restrict__ target, const bf* __restrict__ emb,
                        bf* __restrict__ x_seq, const int* __restrict__ flags) {
    int t = blockIdx.x, b = blockIdx.y, e = threadIdx.x;
    int lab = 0;
    if (t > 0) {
        int idx = b * 30 + (t - 1);
        lab = flags[1] ? target[2 * idx] : target[idx];
    }
    lab = min(max(lab, 0), 96);
    x_seq[(t * NB + b) * ENC + e] = emb[lab * ENC + e];
}

__global__ void k_wt(const bf* __restrict__ ew, bf* __restrict__ wt) {
    int dydx = blockIdx.x, a = blockIdx.y;
    for (int c = threadIdx.x; c < FMAP; c += 256)
        wt[(dydx * ATTN + a) * FMAP + c] = ew[(a * FMAP + c) * 9 + dydx];
}

// zero all of padT (halo rows stay zero; interior overwritten by k_padT)
__global__ void k_zero(unsigned long long* __restrict__ p) {
    p[blockIdx.x * 256 + threadIdx.x] = 0ULL;  // 8B = 4 bf16 each
}

// padT[b][(y+1)*34+(x+1)][c] = bf16(fmap_f32[b][c][y*32+x]); LDS tile transpose
__global__ __launch_bounds__(256) void k_padT(const float* __restrict__ fmapf,
                                              bf* __restrict__ padT) {
    __shared__ bf T3[64 * 258];  // [c_local][hw], stride 258 (odd dw count)
    int b = blockIdx.x, cq = blockIdx.y;  // grid (64, 8)
    int tid = threadIdx.x;
    for (int c_l = 0; c_l < 64; c_l++) {
        float v = fmapf[((size_t)(b * FMAP + cq * 64 + c_l)) * HW + tid];
        T3[c_l * 258 + tid] = f2b(v);
    }
    __syncthreads();
    int c_o = tid & 63, pg = tid >> 6;
    for (int it = 0; it < 64; it++) {
        int pos = it * 4 + pg, y = pos >> 5, x = pos & 31;
        padT[((size_t)b * PPOS + (y + 1) * PW + (x + 1)) * FMAP + cq * 64 + c_o] =
            T3[c_o * 258 + pos];
    }
}

// conv3x3 as MFMA GEMM, A=wt from global, B=padT from global (no LDS).
__global__ __launch_bounds__(256) void k_conv(const bf* __restrict__ padT,
                                              const bf* __restrict__ wt,
                                              const bf* __restrict__ efb,
                                              bf* __restrict__ ef) {
    int b = blockIdx.x, aHalf = blockIdx.y, pHalf = blockIdx.z;
    int tid = threadIdx.x, wv = tid >> 6, lane = tid & 63;
    int q = lane >> 4, l = lane & 15;
    int abase = aHalf * 128 + wv * 32;

    int pbase[8];
#pragma unroll
    for (int nt = 0; nt < 8; nt++) {
        int pos = pHalf * 128 + nt * 16 + l;
        pbase[nt] = (pos >> 5) * PW + (pos & 31);
    }
    const bf* pb = padT + (size_t)b * PPOS * FMAP;

    f32x4 acc[2][8] = {};
    for (int dydx = 0; dydx < 9; dydx++) {
        int poff = (dydx / 3) * PW + (dydx % 3);
        const bf* wtd = wt + ((size_t)dydx * ATTN) * FMAP;
        for (int k0 = 0; k0 < FMAP; k0 += 32) {
            bf16_8 afr[2];
#pragma unroll
            for (int mt = 0; mt < 2; mt++)
                afr[mt] = *(const bf16_8*)(wtd + (abase + mt * 16 + l) * FMAP + k0 + q * 8);
#pragma unroll
            for (int nt = 0; nt < 8; nt++) {
                bf16_8 bfr = *(const bf16_8*)(pb + (size_t)(pbase[nt] + poff) * FMAP + k0 + q * 8);
                acc[0][nt] = mfma16(afr[0], bfr, acc[0][nt]);
                acc[1][nt] = mfma16(afr[1], bfr, acc[1][nt]);
            }
        }
    }
#pragma unroll
    for (int mt = 0; mt < 2; mt++)
#pragma unroll
        for (int nt = 0; nt < 8; nt++) {
            int a0 = abase + mt * 16 + q * 4;
            int pos = pHalf * 128 + nt * 16 + l;
            bf16_4 o;
#pragma unroll
            for (int r = 0; r < 4; r++) o[r] = f2b(acc[mt][nt][r] + b2f(efb[a0 + r]));
            *(bf16_4*)(ef + ((size_t)(b * HW + pos)) * ATTN + a0) = o;
        }
}

// ------------------------- per-step kernels --------------------------------

__global__ void k_lstm0(const bf* __restrict__ xt, const bf* __restrict__ Wih0,
                        const bf* __restrict__ hprev, const bf* __restrict__ Whh0,
                        const bf* __restrict__ bih, const bf* __restrict__ bhh,
                        float* __restrict__ cf, bf* __restrict__ hnew) {
    int d0 = blockIdx.x * 16;
    int wv = threadIdx.x >> 6, lane = threadIdx.x & 63;
    int q = lane >> 4, l = lane & 15;
    f32x4 acc[4] = {};
    for (int k0 = 0; k0 < ENC; k0 += 32) {
        bf16_8 af = *(const bf16_8*)(xt + (wv * 16 + l) * ENC + k0 + q * 8);
#pragma unroll
        for (int g = 0; g < 4; g++) {
            bf16_8 bfr = *(const bf16_8*)(Wih0 + (g * 512 + d0 + l) * ENC + k0 + q * 8);
            acc[g] = mfma16(af, bfr, acc[g]);
        }
    }
    for (int k0 = 0; k0 < DEC; k0 += 32) {
        bf16_8 af = *(const bf16_8*)(hprev + (wv * 16 + l) * DEC + k0 + q * 8);
#pragma unroll
        for (int g = 0; g < 4; g++) {
            bf16_8 bfr = *(const bf16_8*)(Whh0 + (g * 512 + d0 + l) * DEC + k0 + q * 8);
            acc[g] = mfma16(af, bfr, acc[g]);
        }
    }
    int d = d0 + l;
    float bi[4];
#pragma unroll
    for (int g = 0; g < 4; g++) bi[g] = b2f(bih[g * 512 + d]) + b2f(bhh[g * 512 + d]);
#pragma unroll
    for (int r = 0; r < 4; r++) {
        int bb = wv * 16 + q * 4 + r;
        float gi = sigm(acc[0][r] + bi[0]);
        float gf = sigm(acc[1][r] + bi[1]);
        float gg = tanh_f(acc[2][r] + bi[2]);
        float go = sigm(acc[3][r] + bi[3]);
        float c = gf * cf[bb * DEC + d] + gi * gg;
        cf[bb * DEC + d] = c;
        hnew[bb * DEC + d] = f2b(go * tanh_f(c));
    }
}

__global__ void k_lstm1(const bf* __restrict__ h0new, const bf* __restrict__ h1prev,
                        const bf* __restrict__ Wih1, const bf* __restrict__ Whh1,
                        const bf* __restrict__ bih, const bf* __restrict__ bhh,
                        float* __restrict__ cf, bf* __restrict__ hnew) {
    int d0 = blockIdx.x * 16;
    int wv = threadIdx.x >> 6, lane = threadIdx.x & 63;
    int q = lane >> 4, l = lane & 15;
    f32x4 acc[4] = {};
    for (int ph = 0; ph < 2; ph++) {
        const bf* A = ph ? h1prev : h0new;
        const bf* Wp = ph ? Whh1 : Wih1;
        for (int k0 = 0; k0 < DEC; k0 += 32) {
            bf16_8 af = *(const bf16_8*)(A + (wv * 16 + l) * DEC + k0 + q * 8);
#pragma unroll
            for (int g = 0; g < 4; g++) {
                bf16_8 bfr = *(const bf16_8*)(Wp + (g * 512 + d0 + l) * DEC + k0 + q * 8);
                acc[g] = mfma16(af, bfr, acc[g]);
            }
        }
    }
    int d = d0 + l;
    float bi[4];
#pragma unroll
    for (int g = 0; g < 4; g++) bi[g] = b2f(bih[g * 512 + d]) + b2f(bhh[g * 512 + d]);
#pragma unroll
    for (int r = 0; r < 4; r++) {
        int bb = wv * 16 + q * 4 + r;
        float gi = sigm(acc[0][r] + bi[0]);
        float gf = sigm(acc[1][r] + bi[1]);
        float gg = tanh_f(acc[2][r] + bi[2]);
        float go = sigm(acc[3][r] + bi[3]);
        float c = gf * cf[bb * DEC + d] + gi * gg;
        cf[bb * DEC + d] = c;
        hnew[bb * DEC + d] = f2b(go * tanh_f(c));
    }
}

// eh/fch GEMV + score + softmax + glimpse + fc; one block per batch row.
__global__ __launch_bounds__(256) void k_attn(
        int t, const bf* __restrict__ h1new,
        const bf* __restrict__ e_lstm_w, const bf* __restrict__ e_lstm_b,
        const bf* __restrict__ fc_w, const bf* __restrict__ fc_b,
        const bf* __restrict__ a_w, const bf* __restrict__ a_b,
        const bf* __restrict__ ef, const bf* __restrict__ padT,
        float* __restrict__ out_logits, float* __restrict__ out_masks,
        float* __restrict__ out_glimpses) {
    __shared__ float h1s[DEC], ehs[ATTN], fcs[NC2], aws[ATTN], msk[HW],
                     gls[FMAP], red[256];
    int b = blockIdx.x, tid = threadIdx.x;

    for (int i = tid; i < DEC; i += 256) h1s[i] = b2f(h1new[b * DEC + i]);
    aws[tid] = b2f(a_w[tid]);
    __syncthreads();

    // eh[tid] and (tid<98) fch[tid]: GEMV against h1s
    {
        float s = 0.0f;
        const bf16_8* wr = (const bf16_8*)(e_lstm_w + (size_t)tid * DEC);
#pragma unroll 4
        for (int k8 = 0; k8 < DEC / 8; k8++) {
            bf16_8 w8 = wr[k8];
#pragma unroll
            for (int j = 0; j < 8; j++) s += (float)w8[j] * h1s[k8 * 8 + j];
        }
        ehs[tid] = s + b2f(e_lstm_b[tid]);
        if (tid < NC2) {
            float s2 = 0.0f;
            const bf16_8* wr2 = (const bf16_8*)(fc_w + (size_t)tid * (DEC + FMAP));
#pragma unroll 4
            for (int k8 = 0; k8 < DEC / 8; k8++) {
                bf16_8 w8 = wr2[k8];
#pragma unroll
                for (int j = 0; j < 8; j++) s2 += (float)w8[j] * h1s[k8 * 8 + j];
            }
            fcs[tid] = s2 + b2f(fc_b[tid]);
        }
    }
    __syncthreads();

    // score[pos=tid]
    float sc;
    {
        const bf16_8* er = (const bf16_8*)(ef + ((size_t)b * HW + tid) * ATTN);
        float s0 = 0.f, s1 = 0.f, s2 = 0.f, s3 = 0.f;
#pragma unroll 4
        for (int a8 = 0; a8 < ATTN / 8; a8++) {
            bf16_8 e8 = er[a8];
            int a = a8 * 8;
            s0 += aws[a + 0] * tanh_f(ehs[a + 0] + (float)e8[0]);
            s1 += aws[a + 1] * tanh_f(ehs[a + 1] + (float)e8[1]);
            s2 += aws[a + 2] * tanh_f(ehs[a + 2] + (float)e8[2]);
            s3 += aws[a + 3] * tanh_f(ehs[a + 3] + (float)e8[3]);
            s0 += aws[a + 4] * tanh_f(ehs[a + 4] + (float)e8[4]);
            s1 += aws[a + 5] * tanh_f(ehs[a + 5] + (float)e8[5]);
            s2 += aws[a + 6] * tanh_f(ehs[a + 6] + (float)e8[6]);
            s3 += aws[a + 7] * tanh_f(ehs[a + 7] + (float)e8[7]);
        }
        sc = (s0 + s1) + (s2 + s3) + b2f(a_b[0]);
        red[tid] = sc;
    }
    __syncthreads();
    for (int off = 128; off > 0; off >>= 1) {
        if (tid < off) red[tid] = fmaxf(red[tid], red[tid + off]);
        __syncthreads();
    }
    float mx = red[0];
    __syncthreads();
    float ex = __expf(sc - mx);
    red[tid] = ex;
    __syncthreads();
    for (int off = 128; off > 0; off >>= 1) {
        if (tid < off) red[tid] += red[tid + off];
        __syncthreads();
    }
    float mk = ex / red[0];
    msk[tid] = mk;
    out_masks[(b * TT + t) * HW + tid] = mk;
    __syncthreads();

    // glimpse from padT [ppos][c]: thread owns c=2*tid,2*tid+1, coalesced
    {
        int c2 = tid * 2;
        float g0 = 0.f, g1 = 0.f;
        const bf* pb = padT + (size_t)b * PPOS * FMAP;
        for (int y = 0; y < 8; y++) {
            const bf* row0 = pb + (size_t)((y + 1) * PW + 1) * FMAP + c2;
#pragma unroll 8
            for (int x = 0; x < 32; x++) {
                float m = msk[y * 32 + x];
                bf16_2 v = *(const bf16_2*)(row0 + x * FMAP);
                g0 += (float)v[0] * m;
                g1 += (float)v[1] * m;
            }
        }
        gls[c2] = g0;
        gls[c2 + 1] = g1;
        float* og = out_glimpses + ((size_t)b * TT + t) * FMAP;
        og[c2] = g0;
        og[c2 + 1] = g1;
    }
    __syncthreads();

    // logits: glimpse half of fc + precomputed h1 half
    {
        int cls = tid >> 1, half = tid & 1;
        float s = 0.0f;
        if (cls < NC2) {
            const bf16_8* wr =
                (const bf16_8*)(fc_w + (size_t)cls * (DEC + FMAP) + DEC + half * 256);
            const float* act = gls + half * 256;
#pragma unroll 4
            for (int k8 = 0; k8 < 32; k8++) {
                bf16_8 w8 = wr[k8];
#pragma unroll
                for (int j = 0; j < 8; j++) s += (float)w8[j] * act[k8 * 8 + j];
            }
        }
        red[tid] = s;
        __syncthreads();
        if (cls < NC2 && half == 0)
            out_logits[(b * TT + t) * NC2 + cls] = red[tid] + red[tid + 1] + fcs[cls];
    }
}

// ------------------------------ host ---------------------------------------

extern "C" void kernel_launch(void* const* d_in, const int* in_sizes, int n_in,
                              void* d_out, int out_size, void* d_ws, size_t ws_size,
                              hipStream_t stream) {
    float* out = (float*)d_out;
    float* out_logits   = out;
    float* out_masks    = out + 64 * 31 * 98;
    float* out_glimpses = out + 64 * 31 * (98 + 256);

    unsigned char* ws = (unsigned char*)d_ws;
    unsigned long long off = 0;
    auto carve = [&](size_t bytes) {
        unsigned long long o = off;
        off = (off + bytes + 15ULL) & ~15ULL;
        return o;
    };

    unsigned long long o_flags = carve(64);
    static const int cvt_in[N_CVT] = {5, 6, 7, 8, 9, 10, 11, 12, 13, 14, 15, 16, 17, 18, 19, 20, 21};
    static const int cvt_n[N_CVT] = {
        97 * 256, 2048 * 256, 2048 * 512, 2048, 2048,
        2048 * 512, 2048 * 512, 2048, 2048,
        256 * 512, 256, 256 * 512 * 9, 256, 256, 1,
        98 * 1024, 98
    };
    CvtTab tab;
    for (int i = 0; i < N_CVT; i++) {
        tab.src[i] = d_in[cvt_in[i]];
        tab.n[i] = cvt_n[i];
        tab.off[i] = carve((size_t)cvt_n[i] * 2);
    }
    const bf* emb_c    = (const bf*)(ws + tab.off[0]);
    const bf* Wih0_c   = (const bf*)(ws + tab.off[1]);
    const bf* Whh0_c   = (const bf*)(ws + tab.off[2]);
    const bf* bih0_c   = (const bf*)(ws + tab.off[3]);
    const bf* bhh0_c   = (const bf*)(ws + tab.off[4]);
    const bf* Wih1_c   = (const bf*)(ws + tab.off[5]);
    const bf* Whh1_c   = (const bf*)(ws + tab.off[6]);
    const bf* bih1_c   = (const bf*)(ws + tab.off[7]);
    const bf* bhh1_c   = (const bf*)(ws + tab.off[8]);
    const bf* e_lstm_w_c = (const bf*)(ws + tab.off[9]);
    const bf* e_lstm_b_c = (const bf*)(ws + tab.off[10]);
    const bf* e_fmap_w_c = (const bf*)(ws + tab.off[11]);
    const bf* e_fmap_b_c = (const bf*)(ws + tab.off[12]);
    const bf* a_w_c    = (const bf*)(ws + tab.off[13]);
    const bf* a_b_c    = (const bf*)(ws + tab.off[14]);
    const bf* fc_w_c   = (const bf*)(ws + tab.off[15]);
    const bf* fc_b_c   = (const bf*)(ws + tab.off[16]);

    bf*    wt    = (bf*)(ws + carve((size_t)9 * 256 * 512 * 2));
    bf*    ef    = (bf*)(ws + carve((size_t)64 * 256 * 256 * 2));
    bf*    x_seq = (bf*)(ws + carve((size_t)31 * 64 * 256 * 2));
    bf*    h0b   = (bf*)(ws + carve(2 * 65536));
    bf*    h1b   = (bf*)(ws + carve(2 * 65536));
    float* c0f   = (float*)(ws + carve(131072));
    float* c1f   = (float*)(ws + carve(131072));
    bf*    padT  = (bf*)(ws + carve((size_t)NB * PPOS * FMAP * 2));  // 22.28 MB
    int*   flags = (int*)(ws + o_flags);
    // total ~45 MB

    k_detect<<<1, 256, 0, stream>>>((const int*)d_in[3], flags);
    k_cvt<<<dim3(256, N_CVT), 256, 0, stream>>>(tab, ws);
    k_init_state<<<128, 256, 0, stream>>>((const float*)d_in[1], (const float*)d_in[2],
                                          h0b, h1b, c0f, c1f);
    k_embed<<<dim3(TT, NB), 256, 0, stream>>>((const int*)d_in[3], emb_c, x_seq, flags);
    k_wt<<<dim3(9, ATTN), 256, 0, stream>>>(e_fmap_w_c, wt);
    k_zero<<<10880, 256, 0, stream>>>((unsigned long long*)padT);
    k_padT<<<dim3(NB, 8), 256, 0, stream>>>((const float*)d_in[0], padT);
    k_conv<<<dim3(NB, 2, 2), 256, 0, stream>>>(padT, wt, e_fmap_b_c, ef);

    for (int t = 0; t < TT; t++) {
        int cur = t & 1;
        bf* h1new = h1b + (cur ^ 1) * 32768;
        k_lstm0<<<32, 256, 0, stream>>>(x_seq + (size_t)t * NB * ENC, Wih0_c,
                                        h0b + cur * 32768, Whh0_c,
                                        bih0_c, bhh0_c, c0f, h0b + (cur ^ 1) * 32768);
        k_lstm1<<<32, 256, 0, stream>>>(h0b + (cur ^ 1) * 32768, h1b + cur * 32768,
                                        Wih1_c, Whh1_c, bih1_c, bhh1_c, c1f, h1new);
        k_attn<<<NB, 256, 0, stream>>>(t, h1new, e_lstm_w_c, e_lstm_b_c,
                                       fc_w_c, fc_b_c, a_w_c, a_b_c, ef, padT,
                                       out_logits, out_masks, out_glimpses);
    }
}

// Round 9
// 1676.897 us; speedup vs baseline: 2.1767x; 1.7468x over previous
//
#include <hip/hip_runtime.h>
#include <hip/hip_bf16.h>

// ---------------------------------------------------------------------------
// Decoder_996432412985: attention LSTM decoder on MI355X.
// B=64, FMAP=512, ENC=256, DEC=512, ATTN=256, NC+2=98, T+1=31, H=8, W=32.
// Inputs fp32 -> bf16 ws copies; bf16 MFMA + fp32 acc; outputs fp32.
// R9: software-pipelined step loop. lstm0(s), lstm1(s-1), attn(s-2) are
// independent -> ONE regular launch (128 blocks, no grid.sync) per s=0..32:
// 33 launches instead of 93; per-launch time = max(phase), not sum.
// Conv: R5 LDS-MFMA but staged from padT (straight copy, no transpose-write
// conflicts). R8's global-operand conv (212us, uncoalesced) reverted.
// ---------------------------------------------------------------------------

typedef __bf16 bf16_8 __attribute__((ext_vector_type(8)));
typedef __bf16 bf16_4 __attribute__((ext_vector_type(4)));
typedef __bf16 bf16_2 __attribute__((ext_vector_type(2)));
typedef float f32x4 __attribute__((ext_vector_type(4)));

typedef __hip_bfloat16 bf;

__device__ __forceinline__ float b2f(bf h) { return __bfloat162float(h); }
__device__ __forceinline__ bf f2b(float f) { return __float2bfloat16(f); }
__device__ __forceinline__ float sigm(float x) { return 1.0f / (1.0f + __expf(-x)); }
__device__ __forceinline__ float tanh_f(float x) { return 1.0f - 2.0f / (1.0f + __expf(2.0f * x)); }
__device__ __forceinline__ f32x4 mfma16(bf16_8 a, bf16_8 b, f32x4 c) {
    return __builtin_amdgcn_mfma_f32_16x16x32_bf16(a, b, c, 0, 0, 0);
}

#define NB 64
#define FMAP 512
#define ENC 256
#define DEC 512
#define ATTN 256
#define NC2 98
#define TT 31
#define HW 256
#define PW 34
#define PPOS 340  // 10*34 padded spatial

// ------------------------- dtype normalization -----------------------------

__global__ void k_detect(const int* __restrict__ t32, int* __restrict__ flags) {
    __shared__ int i64f;
    int tid = threadIdx.x;
    if (tid == 0) i64f = 1;
    __syncthreads();
    for (int i = tid; i < 960; i += 256)
        if (t32[2 * i + 1] != 0) i64f = 0;
    __syncthreads();
    if (tid == 0) { flags[0] = 0; flags[1] = i64f; }
}

#define N_CVT 17
struct CvtTab {
    const void* src[N_CVT];
    unsigned long long off[N_CVT];
    int n[N_CVT];
};

__global__ void k_cvt(CvtTab tab, unsigned char* __restrict__ ws) {
    int id = blockIdx.y;
    int n = tab.n[id];
    bf* dst = (bf*)(ws + tab.off[id]);
    const float* sf = (const float*)tab.src[id];
    for (int i = blockIdx.x * 256 + threadIdx.x; i < n; i += 256 * gridDim.x)
        dst[i] = f2b(sf[i]);
}

// ------------------------- prep kernels ------------------------------------

// initial h/c are state(-1): parity (-1)&1 = 1 -> second half of ping-pong
__global__ void k_init_state(const float* __restrict__ h0, const float* __restrict__ c0,
                             bf* __restrict__ h0b, bf* __restrict__ h1b,
                             float* __restrict__ c0f, float* __restrict__ c1f) {
    int i = blockIdx.x * 256 + threadIdx.x;
    if (i >= NB * DEC) return;
    h0b[32768 + i] = f2b(h0[i]);
    h1b[32768 + i] = f2b(h0[NB * DEC + i]);
    c0f[i] = c0[i];
    c1f[i] = c0[NB * DEC + i];
}

__global__ void k_embed(const int* __restrict__ target, const bf* __restrict__ emb,
                        bf* __restrict__ x_seq, const int* __restrict__ flags) {
    int t = blockIdx.x, b = blockIdx.y, e = threadIdx.x;
    int lab = 0;
    if (t > 0) {
        int idx = b * 30 + (t - 1);
        lab = flags[1] ? target[2 * idx] : target[idx];
    }
    lab = min(max(lab, 0), 96);
    x_seq[(t * NB + b) * ENC + e] = emb[lab * ENC + e];
}

__global__ void k_wt(const bf* __restrict__ ew, bf* __restrict__ wt) {
    int dydx = blockIdx.x, a = blockIdx.y;
    for (int c = threadIdx.x; c < FMAP; c += 256)
        wt[(dydx * ATTN + a) * FMAP + c] = ew[(a * FMAP + c) * 9 + dydx];
}

// zero all of padT (halo rows stay zero; interior overwritten by k_padT)
__global__ void k_zero(unsigned long long* __restrict__ p) {
    p[blockIdx.x * 256 + threadIdx.x] = 0ULL;
}

// padT[b][(y+1)*34+(x+1)][c] = bf16(fmap_f32[b][c][y*32+x]); LDS tile transpose
__global__ __launch_bounds__(256) void k_padT(const float* __restrict__ fmapf,
                                              bf* __restrict__ padT) {
    __shared__ bf T3[64 * 258];
    int b = blockIdx.x, cq = blockIdx.y;  // grid (64, 8)
    int tid = threadIdx.x;
    for (int c_l = 0; c_l < 64; c_l++) {
        float v = fmapf[((size_t)(b * FMAP + cq * 64 + c_l)) * HW + tid];
        T3[c_l * 258 + tid] = f2b(v);
    }
    __syncthreads();
    int c_o = tid & 63, pg = tid >> 6;
    for (int it = 0; it < 64; it++) {
        int pos = it * 4 + pg, y = pos >> 5, x = pos & 31;
        padT[((size_t)b * PPOS + (y + 1) * PW + (x + 1)) * FMAP + cq * 64 + c_o] =
            T3[c_o * 258 + pos];
    }
}

// conv3x3 as MFMA GEMM: LDS tile staged from padT (straight copy, coalesced).
__global__ __launch_bounds__(256) void k_conv(const bf* __restrict__ padT,
                                              const bf* __restrict__ wt,
                                              const bf* __restrict__ efb,
                                              bf* __restrict__ ef) {
    __shared__ __align__(16) bf T[257 * 72];
    int b = blockIdx.x, aHalf = blockIdx.y, pHalf = blockIdx.z;
    int tid = threadIdx.x, wv = tid >> 6, lane = tid & 63;
    int q = lane >> 4, l = lane & 15;
    int abase = aHalf * 128 + wv * 32;

    for (int i = tid; i < 72; i += 256) T[256 * 72 + i] = f2b(0.0f);  // halo row

    const bf* pb = padT + (size_t)b * PPOS * FMAP;
    f32x4 acc[2][8] = {};
    for (int cQ = 0; cQ < 8; cQ++) {
        __syncthreads();
        // stage 256 rows x 64 c: straight copy, b128 both sides
#pragma unroll
        for (int j = 0; j < 8; j++) {
            int chunk = j * 256 + tid;       // 2048 chunks of 8 bf16
            int row = chunk >> 3, g = chunk & 7;
            int ppos = 35 + (row >> 5) * PW + (row & 31);
            *(bf16_8*)(T + row * 72 + g * 8) =
                *(const bf16_8*)(pb + (size_t)ppos * FMAP + cQ * 64 + g * 8);
        }
        __syncthreads();
        for (int dydx = 0; dydx < 9; dydx++) {
            int dy = dydx / 3, dx = dydx % 3;
            int rowv[8];
#pragma unroll
            for (int nt = 0; nt < 8; nt++) {
                int y = pHalf * 4 + (nt >> 1);
                int yp = y + dy - 1;
                int x = (nt & 1) * 16 + l;
                int xp = x + dx - 1;
                bool ok = (yp >= 0 && yp < 8 && xp >= 0 && xp < 32);
                rowv[nt] = ok ? (yp * 32 + xp) : 256;
            }
            const bf* wtd = wt + ((size_t)dydx * ATTN) * FMAP;
#pragma unroll
            for (int ck = 0; ck < 2; ck++) {
                int kg = cQ * 64 + ck * 32 + q * 8;
                bf16_8 afr[2];
#pragma unroll
                for (int mt = 0; mt < 2; mt++)
                    afr[mt] = *(const bf16_8*)(wtd + (abase + mt * 16 + l) * FMAP + kg);
#pragma unroll
                for (int nt = 0; nt < 8; nt++) {
                    bf16_8 bfr = *(const bf16_8*)(T + rowv[nt] * 72 + ck * 32 + q * 8);
                    acc[0][nt] = mfma16(afr[0], bfr, acc[0][nt]);
                    acc[1][nt] = mfma16(afr[1], bfr, acc[1][nt]);
                }
            }
        }
    }
#pragma unroll
    for (int mt = 0; mt < 2; mt++)
#pragma unroll
        for (int nt = 0; nt < 8; nt++) {
            int a0 = abase + mt * 16 + q * 4;
            int pos = pHalf * 128 + nt * 16 + l;
            bf16_4 o;
#pragma unroll
            for (int r = 0; r < 4; r++) o[r] = f2b(acc[mt][nt][r] + b2f(efb[a0 + r]));
            *(bf16_4*)(ef + ((size_t)(b * HW + pos)) * ATTN + a0) = o;
        }
}

// ---------------- pipelined mega-step kernel (regular launch) ---------------
// Launch s: blocks 32..63 -> lstm0(s) [s<=30]; blocks 0..31 -> lstm1(s-1)
// [1<=s<=31]; blocks 64..127 -> attn(s-2) [s>=2]. Phases are independent;
// all cross-phase deps are satisfied by the PREVIOUS launch.
// State parity: state(t) lives at buffer half (t&1); init wrote parity 1.

struct StepArgs {
    const bf *x_seq, *Wih0, *Whh0, *bih0, *bhh0, *Wih1, *Whh1, *bih1, *bhh1;
    const bf *e_lstm_w, *e_lstm_b, *fc_w, *fc_b, *a_w, *a_b, *ef, *padT;
    bf *h0b, *h1b;
    float *c0f, *c1f;
    float *out_logits, *out_masks, *out_glimpses;
};

__global__ __launch_bounds__(256) void k_mega(int s, StepArgs A) {
    const int blk = blockIdx.x, tid = threadIdx.x;
    const int wv = tid >> 6, lane = tid & 63;
    const int q = lane >> 4, l = lane & 15;
    const int pcur = s & 1, pprev = (s + 1) & 1;

    __shared__ float h1s[DEC], ehs[ATTN], fcs[NC2], aws[ATTN], msk[HW],
                     gls[FMAP], red[256];

    if (blk >= 32 && blk < 64) {
        // ---------------- lstm0(s) ----------------
        if (s <= 30) {
            int d0 = (blk - 32) * 16;
            const bf* xt = A.x_seq + (size_t)s * NB * ENC;
            const bf* hprev = A.h0b + pprev * 32768;
            bf* hnew = A.h0b + pcur * 32768;
            f32x4 acc[4] = {};
            for (int k0 = 0; k0 < ENC; k0 += 32) {
                bf16_8 af = *(const bf16_8*)(xt + (wv * 16 + l) * ENC + k0 + q * 8);
#pragma unroll
                for (int g = 0; g < 4; g++) {
                    bf16_8 bfr = *(const bf16_8*)(A.Wih0 + (g * 512 + d0 + l) * ENC + k0 + q * 8);
                    acc[g] = mfma16(af, bfr, acc[g]);
                }
            }
            for (int k0 = 0; k0 < DEC; k0 += 32) {
                bf16_8 af = *(const bf16_8*)(hprev + (wv * 16 + l) * DEC + k0 + q * 8);
#pragma unroll
                for (int g = 0; g < 4; g++) {
                    bf16_8 bfr = *(const bf16_8*)(A.Whh0 + (g * 512 + d0 + l) * DEC + k0 + q * 8);
                    acc[g] = mfma16(af, bfr, acc[g]);
                }
            }
            int d = d0 + l;
            float bi[4];
#pragma unroll
            for (int g = 0; g < 4; g++)
                bi[g] = b2f(A.bih0[g * 512 + d]) + b2f(A.bhh0[g * 512 + d]);
#pragma unroll
            for (int r = 0; r < 4; r++) {
                int bb = wv * 16 + q * 4 + r;
                float gi = sigm(acc[0][r] + bi[0]);
                float gf = sigm(acc[1][r] + bi[1]);
                float gg = tanh_f(acc[2][r] + bi[2]);
                float go = sigm(acc[3][r] + bi[3]);
                float c = gf * A.c0f[bb * DEC + d] + gi * gg;
                A.c0f[bb * DEC + d] = c;
                hnew[bb * DEC + d] = f2b(go * tanh_f(c));
            }
        }
    } else if (blk < 32) {
        // ---------------- lstm1(s-1) ----------------
        if (s >= 1 && s <= 31) {
            int d0 = blk * 16;
            const bf* h0n = A.h0b + pprev * 32768;  // h0 state(s-1)
            const bf* h1p = A.h1b + pcur * 32768;   // h1 state(s-2)
            bf* h1n = A.h1b + pprev * 32768;        // h1 state(s-1)
            f32x4 acc[4] = {};
            for (int ph = 0; ph < 2; ph++) {
                const bf* Ain = ph ? h1p : h0n;
                const bf* Wp = ph ? A.Whh1 : A.Wih1;
                for (int k0 = 0; k0 < DEC; k0 += 32) {
                    bf16_8 af = *(const bf16_8*)(Ain + (wv * 16 + l) * DEC + k0 + q * 8);
#pragma unroll
                    for (int g = 0; g < 4; g++) {
                        bf16_8 bfr = *(const bf16_8*)(Wp + (g * 512 + d0 + l) * DEC + k0 + q * 8);
                        acc[g] = mfma16(af, bfr, acc[g]);
                    }
                }
            }
            int d = d0 + l;
            float bi[4];
#pragma unroll
            for (int g = 0; g < 4; g++)
                bi[g] = b2f(A.bih1[g * 512 + d]) + b2f(A.bhh1[g * 512 + d]);
#pragma unroll
            for (int r = 0; r < 4; r++) {
                int bb = wv * 16 + q * 4 + r;
                float gi = sigm(acc[0][r] + bi[0]);
                float gf = sigm(acc[1][r] + bi[1]);
                float gg = tanh_f(acc[2][r] + bi[2]);
                float go = sigm(acc[3][r] + bi[3]);
                float c = gf * A.c1f[bb * DEC + d] + gi * gg;
                A.c1f[bb * DEC + d] = c;
                h1n[bb * DEC + d] = f2b(go * tanh_f(c));
            }
        }
    } else {
        // ---------------- attn(s-2), b = blk-64 ----------------
        if (s >= 2) {
            int b = blk - 64, t = s - 2;
            const bf* h1 = A.h1b + pcur * 32768;  // h1 state(s-2)

            for (int i = tid; i < DEC; i += 256) h1s[i] = b2f(h1[b * DEC + i]);
            aws[tid] = b2f(A.a_w[tid]);
            __syncthreads();

            // eh[tid] and (tid<98) fch[tid]: GEMV against h1s
            {
                float s1 = 0.0f;
                const bf16_8* wr = (const bf16_8*)(A.e_lstm_w + (size_t)tid * DEC);
#pragma unroll 4
                for (int k8 = 0; k8 < DEC / 8; k8++) {
                    bf16_8 w8 = wr[k8];
#pragma unroll
                    for (int j = 0; j < 8; j++) s1 += (float)w8[j] * h1s[k8 * 8 + j];
                }
                ehs[tid] = s1 + b2f(A.e_lstm_b[tid]);
                if (tid < NC2) {
                    float s2 = 0.0f;
                    const bf16_8* wr2 = (const bf16_8*)(A.fc_w + (size_t)tid * (DEC + FMAP));
#pragma unroll 4
                    for (int k8 = 0; k8 < DEC / 8; k8++) {
                        bf16_8 w8 = wr2[k8];
#pragma unroll
                        for (int j = 0; j < 8; j++) s2 += (float)w8[j] * h1s[k8 * 8 + j];
                    }
                    fcs[tid] = s2 + b2f(A.fc_b[tid]);
                }
            }
            __syncthreads();

            // score[pos=tid]
            float sc;
            {
                const bf16_8* er = (const bf16_8*)(A.ef + ((size_t)b * HW + tid) * ATTN);
                float s0 = 0.f, s1 = 0.f, s2 = 0.f, s3 = 0.f;
#pragma unroll 4
                for (int a8 = 0; a8 < ATTN / 8; a8++) {
                    bf16_8 e8 = er[a8];
                    int a = a8 * 8;
                    s0 += aws[a + 0] * tanh_f(ehs[a + 0] + (float)e8[0]);
                    s1 += aws[a + 1] * tanh_f(ehs[a + 1] + (float)e8[1]);
                    s2 += aws[a + 2] * tanh_f(ehs[a + 2] + (float)e8[2]);
                    s3 += aws[a + 3] * tanh_f(ehs[a + 3] + (float)e8[3]);
                    s0 += aws[a + 4] * tanh_f(ehs[a + 4] + (float)e8[4]);
                    s1 += aws[a + 5] * tanh_f(ehs[a + 5] + (float)e8[5]);
                    s2 += aws[a + 6] * tanh_f(ehs[a + 6] + (float)e8[6]);
                    s3 += aws[a + 7] * tanh_f(ehs[a + 7] + (float)e8[7]);
                }
                sc = (s0 + s1) + (s2 + s3) + b2f(A.a_b[0]);
                red[tid] = sc;
            }
            __syncthreads();
            for (int off = 128; off > 0; off >>= 1) {
                if (tid < off) red[tid] = fmaxf(red[tid], red[tid + off]);
                __syncthreads();
            }
            float mx = red[0];
            __syncthreads();
            float ex = __expf(sc - mx);
            red[tid] = ex;
            __syncthreads();
            for (int off = 128; off > 0; off >>= 1) {
                if (tid < off) red[tid] += red[tid + off];
                __syncthreads();
            }
            float mk = ex / red[0];
            msk[tid] = mk;
            A.out_masks[(b * TT + t) * HW + tid] = mk;
            __syncthreads();

            // glimpse from padT [ppos][c]: thread owns c=2*tid, 2*tid+1
            {
                int c2 = tid * 2;
                float g0 = 0.f, g1 = 0.f;
                const bf* pb = A.padT + (size_t)b * PPOS * FMAP;
                for (int y = 0; y < 8; y++) {
                    const bf* row0 = pb + (size_t)((y + 1) * PW + 1) * FMAP + c2;
#pragma unroll 8
                    for (int x = 0; x < 32; x++) {
                        float m = msk[y * 32 + x];
                        bf16_2 v = *(const bf16_2*)(row0 + x * FMAP);
                        g0 += (float)v[0] * m;
                        g1 += (float)v[1] * m;
                    }
                }
                gls[c2] = g0;
                gls[c2 + 1] = g1;
                float* og = A.out_glimpses + ((size_t)b * TT + t) * FMAP;
                og[c2] = g0;
                og[c2 + 1] = g1;
            }
            __syncthreads();

            // logits: glimpse half of fc + precomputed h1 half
            {
                int cls = tid >> 1, half = tid & 1;
                float s2 = 0.0f;
                if (cls < NC2) {
                    const bf16_8* wr =
                        (const bf16_8*)(A.fc_w + (size_t)cls * (DEC + FMAP) + DEC + half * 256);
                    const float* act = gls + half * 256;
#pragma unroll 4
                    for (int k8 = 0; k8 < 32; k8++) {
                        bf16_8 w8 = wr[k8];
#pragma unroll
                        for (int j = 0; j < 8; j++) s2 += (float)w8[j] * act[k8 * 8 + j];
                    }
                }
                red[tid] = s2;
                __syncthreads();
                if (cls < NC2 && half == 0)
                    A.out_logits[(b * TT + t) * NC2 + cls] = red[tid] + red[tid + 1] + fcs[cls];
            }
        }
    }
}

// ------------------------------ host ---------------------------------------

extern "C" void kernel_launch(void* const* d_in, const int* in_sizes, int n_in,
                              void* d_out, int out_size, void* d_ws, size_t ws_size,
                              hipStream_t stream) {
    float* out = (float*)d_out;
    float* out_logits   = out;
    float* out_masks    = out + 64 * 31 * 98;
    float* out_glimpses = out + 64 * 31 * (98 + 256);

    unsigned char* ws = (unsigned char*)d_ws;
    unsigned long long off = 0;
    auto carve = [&](size_t bytes) {
        unsigned long long o = off;
        off = (off + bytes + 15ULL) & ~15ULL;
        return o;
    };

    unsigned long long o_flags = carve(64);
    static const int cvt_in[N_CVT] = {5, 6, 7, 8, 9, 10, 11, 12, 13, 14, 15, 16, 17, 18, 19, 20, 21};
    static const int cvt_n[N_CVT] = {
        97 * 256, 2048 * 256, 2048 * 512, 2048, 2048,
        2048 * 512, 2048 * 512, 2048, 2048,
        256 * 512, 256, 256 * 512 * 9, 256, 256, 1,
        98 * 1024, 98
    };
    CvtTab tab;
    for (int i = 0; i < N_CVT; i++) {
        tab.src[i] = d_in[cvt_in[i]];
        tab.n[i] = cvt_n[i];
        tab.off[i] = carve((size_t)cvt_n[i] * 2);
    }
    const bf* emb_c    = (const bf*)(ws + tab.off[0]);
    const bf* Wih0_c   = (const bf*)(ws + tab.off[1]);
    const bf* Whh0_c   = (const bf*)(ws + tab.off[2]);
    const bf* bih0_c   = (const bf*)(ws + tab.off[3]);
    const bf* bhh0_c   = (const bf*)(ws + tab.off[4]);
    const bf* Wih1_c   = (const bf*)(ws + tab.off[5]);
    const bf* Whh1_c   = (const bf*)(ws + tab.off[6]);
    const bf* bih1_c   = (const bf*)(ws + tab.off[7]);
    const bf* bhh1_c   = (const bf*)(ws + tab.off[8]);
    const bf* e_lstm_w_c = (const bf*)(ws + tab.off[9]);
    const bf* e_lstm_b_c = (const bf*)(ws + tab.off[10]);
    const bf* e_fmap_w_c = (const bf*)(ws + tab.off[11]);
    const bf* e_fmap_b_c = (const bf*)(ws + tab.off[12]);
    const bf* a_w_c    = (const bf*)(ws + tab.off[13]);
    const bf* a_b_c    = (const bf*)(ws + tab.off[14]);
    const bf* fc_w_c   = (const bf*)(ws + tab.off[15]);
    const bf* fc_b_c   = (const bf*)(ws + tab.off[16]);

    bf*    wt    = (bf*)(ws + carve((size_t)9 * 256 * 512 * 2));
    bf*    ef    = (bf*)(ws + carve((size_t)64 * 256 * 256 * 2));
    bf*    x_seq = (bf*)(ws + carve((size_t)31 * 64 * 256 * 2));
    bf*    h0b   = (bf*)(ws + carve(2 * 65536));
    bf*    h1b   = (bf*)(ws + carve(2 * 65536));
    float* c0f   = (float*)(ws + carve(131072));
    float* c1f   = (float*)(ws + carve(131072));
    bf*    padT  = (bf*)(ws + carve((size_t)NB * PPOS * FMAP * 2));  // 22.28 MB
    int*   flags = (int*)(ws + o_flags);

    k_detect<<<1, 256, 0, stream>>>((const int*)d_in[3], flags);
    k_cvt<<<dim3(256, N_CVT), 256, 0, stream>>>(tab, ws);
    k_init_state<<<128, 256, 0, stream>>>((const float*)d_in[1], (const float*)d_in[2],
                                          h0b, h1b, c0f, c1f);
    k_embed<<<dim3(TT, NB), 256, 0, stream>>>((const int*)d_in[3], emb_c, x_seq, flags);
    k_wt<<<dim3(9, ATTN), 256, 0, stream>>>(e_fmap_w_c, wt);
    k_zero<<<10880, 256, 0, stream>>>((unsigned long long*)padT);
    k_padT<<<dim3(NB, 8), 256, 0, stream>>>((const float*)d_in[0], padT);
    k_conv<<<dim3(NB, 2, 2), 256, 0, stream>>>(padT, wt, e_fmap_b_c, ef);

    StepArgs sa;
    sa.x_seq = x_seq; sa.Wih0 = Wih0_c; sa.Whh0 = Whh0_c;
    sa.bih0 = bih0_c; sa.bhh0 = bhh0_c;
    sa.Wih1 = Wih1_c; sa.Whh1 = Whh1_c; sa.bih1 = bih1_c; sa.bhh1 = bhh1_c;
    sa.e_lstm_w = e_lstm_w_c; sa.e_lstm_b = e_lstm_b_c;
    sa.fc_w = fc_w_c; sa.fc_b = fc_b_c; sa.a_w = a_w_c; sa.a_b = a_b_c;
    sa.ef = ef; sa.padT = padT;
    sa.h0b = h0b; sa.h1b = h1b; sa.c0f = c0f; sa.c1f = c1f;
    sa.out_logits = out_logits; sa.out_masks = out_masks;
    sa.out_glimpses = out_glimpses;

    for (int s = 0; s <= 32; s++)
        k_mega<<<128, 256, 0, stream>>>(s, sa);
}